// Round 2
// baseline (2123.788 us; speedup 1.0000x reference)
//
#include <hip/hip_runtime.h>
#include <math.h>

#define DIMC 64
#define C2 340
#define HID 170
#define IMG 256
#define HW 65536          // 256*256
#define ICP 384           // channels padded to 6*64

// ws float offsets (weights area), z chunk buffer follows
#define OFF_WT  0          // Wt[384 ic][64 in]  (= W_in[o(ic)][in], zero pad)     24576 f
#define OFF_KT  24576      // Kt[384 ic][64 d]   (= K_{o(ic)}[d1*8+d2], zero pad)  24576 f
#define OFF_WDI 49152      // wdwI[9 t][340 ic] interleaved depthwise weights       3060 f
#define OFF_WOT 52212      // WoutT[170 c][64 o]                                   10880 f
#define OFF_Z   63104      // z chunk: [nrh*8*256 pix][340 ic] floats (adaptive)

// interleaved channel position: orig o<170 -> 2o ; o>=170 -> 2(o-170)+1
__device__ __forceinline__ int ipos(int o) { return (o < HID) ? (o << 1) : (((o - HID) << 1) + 1); }

// ---------------------------------------------------------------------------
// K_c[d1][d2] = (1/64) sum_{k1<8,k2<5} a(k2)*F[c][k1][k2]*cos(2pi(k1 d1+k2 d2)/8),
// a=1 for k2 in {0,4} else 2.  (rfft2 -> *realF -> irfft2 == circular conv by K.)
// Stored lane-major by interleaved channel: Kt[ic][d].
// ---------------------------------------------------------------------------
__global__ void k_prep_k(const float* __restrict__ f, float* __restrict__ ws) {
    __shared__ float ct[8];
    int c = blockIdx.x;      // 0..383 (>=340 writes zero pad)
    int d = threadIdx.x;     // 0..63
    if (d < 8) {
        const float S = 0.70710678118654752440f;
        float v;
        switch (d) {
            case 0: v = 1.f; break;
            case 1: v = S; break;
            case 2: v = 0.f; break;
            case 3: v = -S; break;
            case 4: v = -1.f; break;
            case 5: v = -S; break;
            case 6: v = 0.f; break;
            default: v = S; break;
        }
        ct[d] = v;
    }
    __syncthreads();
    if (c >= C2) {
        ws[OFF_KT + (size_t)c * 64 + d] = 0.f;
        return;
    }
    int d1 = d >> 3, d2 = d & 7;
    float acc = 0.f;
    #pragma unroll
    for (int k1 = 0; k1 < 8; ++k1) {
        #pragma unroll
        for (int k2 = 0; k2 < 5; ++k2) {
            float a = (k2 == 0 || k2 == 4) ? 1.f : 2.f;
            acc += a * f[c * 40 + k1 * 5 + k2] * ct[(k1 * d1 + k2 * d2) & 7];
        }
    }
    ws[OFF_KT + (size_t)ipos(c) * 64 + d] = acc * (1.f / 64.f);
}

__global__ void k_prep_w(const float* __restrict__ Win, const float* __restrict__ Wdw,
                         const float* __restrict__ Wout, float* __restrict__ ws) {
    int t = blockIdx.x * 256 + threadIdx.x;      // grid 96*256 = 24576
    if (t < ICP * 64) {              // Wt[ic][in]
        int ic = t >> 6, in = t & 63;
        float v = 0.f;
        if (ic < C2) {
            int o = (ic & 1) ? ((ic >> 1) + HID) : (ic >> 1);
            v = Win[o * DIMC + in];
        }
        ws[OFF_WT + (size_t)t] = v;
    }
    if (t < 9 * C2) {                // wdwI (interleaved depthwise weights)
        int tt = t / C2, ic = t % C2;
        int o = (ic & 1) ? ((ic >> 1) + HID) : (ic >> 1);
        ws[OFF_WDI + tt * C2 + ic] = Wdw[o * 9 + tt];
    }
    if (t < HID * 64) {              // WoutT
        int c = t >> 6, o = t & 63;
        ws[OFF_WOT + t] = Wout[o * HID + c];
    }
}

// ---------------------------------------------------------------------------
// Fused project_in + per-channel 8x8 circular conv.  One block per patch,
// 6 waves x 64 interleaved channels; lane = channel.
//   - x patch staged to LDS [in][pix]; read as wave-uniform b128 broadcasts
//   - projection accumulates p[64 pix] in VGPRs
//   - circular conv fully register-resident (K[64] per lane), 4096 FMA unrolled
//   - z stores coalesced: pixel-major z[pix][ic], lanes cover contiguous 256B
// ---------------------------------------------------------------------------
__global__ __launch_bounds__(384, 2) void k_proj_conv(const float* __restrict__ x,
                                                      const float* __restrict__ ws,
                                                      float* __restrict__ z,
                                                      int b, int pr0, int nr) {
    __shared__ float xs[64 * 64];            // [in][pix] 16 KB
    int blk = blockIdx.x;
    int pyl = blk >> 5, px = blk & 31;
    int py = pr0 + pyl;
    int tid = threadIdx.x;
    int w = tid >> 6, lane = tid & 63;
    int ic = (w << 6) + lane;                // interleaved channel, 0..383
    bool icv = ic < C2;

    // stage x patch  [in][8x8] -> xs[in][pix]
    const float* xb = x + (size_t)b * DIMC * HW + (size_t)(py * 8) * IMG + px * 8;
    for (int u = tid; u < 1024; u += 384) {
        int in = u >> 4, rem = u & 15;
        int r = rem >> 1, h = rem & 1;
        *(float4*)&xs[in * 64 + r * 8 + h * 4] =
            *(const float4*)(xb + (size_t)in * HW + r * IMG + h * 4);
    }
    __syncthreads();

    // projection: p[pix] = sum_in Wt[ic][in] * xs[in][pix]
    float p[64];
    #pragma unroll
    for (int i = 0; i < 64; ++i) p[i] = 0.f;
    const float4* Wq = (const float4*)(ws + OFF_WT) + (size_t)ic * 16;
    for (int q = 0; q < 16; ++q) {
        float4 wv = Wq[q];                    // per-lane, L2-resident
        float wj[4] = {wv.x, wv.y, wv.z, wv.w};
        #pragma unroll
        for (int j = 0; j < 4; ++j) {
            const float4* xr = (const float4*)(xs + (q * 4 + j) * 64);
            #pragma unroll
            for (int pq = 0; pq < 16; ++pq) {
                float4 xv = xr[pq];           // wave-uniform broadcast
                p[pq * 4 + 0] += wj[j] * xv.x;
                p[pq * 4 + 1] += wj[j] * xv.y;
                p[pq * 4 + 2] += wj[j] * xv.z;
                p[pq * 4 + 3] += wj[j] * xv.w;
            }
        }
    }

    // load this lane's circular-conv kernel K[64]
    float K[64];
    const float4* Kq = (const float4*)(ws + OFF_KT) + (size_t)ic * 16;
    #pragma unroll
    for (int q = 0; q < 16; ++q) {
        float4 kv = Kq[q];
        K[q * 4 + 0] = kv.x; K[q * 4 + 1] = kv.y;
        K[q * 4 + 2] = kv.z; K[q * 4 + 3] = kv.w;
    }

    // circular 8x8 conv, all in registers; store row-by-row (coalesced over ic)
    #pragma unroll
    for (int d1 = 0; d1 < 8; ++d1) {
        float zr[8];
        #pragma unroll
        for (int i = 0; i < 8; ++i) zr[i] = 0.f;
        #pragma unroll
        for (int e1 = 0; e1 < 8; ++e1) {
            const int r1 = (d1 - e1) & 7;
            #pragma unroll
            for (int e2 = 0; e2 < 8; ++e2) {
                float pv = p[e1 * 8 + e2];
                #pragma unroll
                for (int d2 = 0; d2 < 8; ++d2)
                    zr[d2] += K[r1 * 8 + ((d2 - e2) & 7)] * pv;
            }
        }
        if (icv) {
            float* zp = z + ((size_t)((pyl * 8 + d1) * IMG + px * 8)) * C2 + ic;
            #pragma unroll
            for (int d2 = 0; d2 < 8; ++d2) zp[(size_t)d2 * C2] = zr[d2];
        }
    }
}

// ---------------------------------------------------------------------------
// Fused depthwise 3x3 (zero pad) + exact GELU-GLU + project_out GEMM.
// Phase A: lane = interleaved channel (coalesced b32 z taps, wave-uniform
// bounds), GLU pair via shfl_xor(.,1).  Phase B: 16 out-ch register blocking.
// ---------------------------------------------------------------------------
__device__ __forceinline__ float gelu_exact(float v) {
    return 0.5f * v * (1.f + erff(v * 0.70710678118654752440f));
}

__global__ __launch_bounds__(256) void k_post(const float* __restrict__ z,
                                              const float* __restrict__ ws,
                                              float* __restrict__ out,
                                              int b, int tr0, int pr0h, int nrh) {
    __shared__ float gbuf[HID * 65];     // stride 65: conflict-free writes/reads, 44.2 KB
    int blk = blockIdx.x;
    int ty = tr0 + (blk >> 5), tx = blk & 31;
    int tid = threadIdx.x;
    int w = tid >> 6, lane = tid & 63;
    int gy0 = ty * 8, gx0 = tx * 8;
    int ybase = pr0h * 8;

    // Phase A: 12 tasks = 6 ic-groups x 2 pixel-halves, 3 per wave
    for (int task = w; task < 12; task += 4) {
        int g = task >> 1, ph = task & 1;
        int ic = (g << 6) + lane;
        bool icv = ic < C2;
        float wt[9];
        #pragma unroll
        for (int t = 0; t < 9; ++t) wt[t] = icv ? ws[OFF_WDI + t * C2 + ic] : 0.f;
        int o = ic >> 1;
        for (int pp = 0; pp < 32; ++pp) {
            int pix = (ph << 5) + pp;
            int yy = gy0 + (pix >> 3), xx = gx0 + (pix & 7);
            const float* zrow = z + ((size_t)(yy - ybase) * IMG + xx) * C2 + ic;
            float acc = 0.f;
            #pragma unroll
            for (int t = 0; t < 9; ++t) {
                const int dy = t / 3 - 1, dx = t % 3 - 1;
                bool ok = icv && ((unsigned)(yy + dy) < (unsigned)IMG) &&
                          ((unsigned)(xx + dx) < (unsigned)IMG);
                if (ok) acc += wt[t] * zrow[(dy * IMG + dx) * C2];
            }
            float prt = __shfl_xor(acc, 1);          // partner (dw2) value
            if (icv && !(lane & 1))
                gbuf[o * 65 + pix] = gelu_exact(acc) * prt;
        }
    }
    __syncthreads();

    // Phase B: project_out, 4 waves x 16 out channels, lane = pixel
    int ob = __builtin_amdgcn_readfirstlane((tid >> 6) * 16);
    float acc[16];
    #pragma unroll
    for (int k = 0; k < 16; ++k) acc[k] = 0.f;
    const float* WoT = ws + OFF_WOT;
    int yy = gy0 + (lane >> 3), xx = gx0 + (lane & 7);
    for (int c = 0; c < HID; ++c) {
        float gv = gbuf[c * 65 + lane];
        const float* wp = WoT + c * 64 + ob;         // uniform -> s_load_dwordx16
        #pragma unroll
        for (int k = 0; k < 16; ++k) acc[k] += wp[k] * gv;
    }
    #pragma unroll
    for (int k = 0; k < 16; ++k)
        out[((size_t)b * 64 + ob + k) * HW + (size_t)yy * IMG + xx] = acc[k];
}

// ---------------------------------------------------------------------------
extern "C" void kernel_launch(void* const* d_in, const int* in_sizes, int n_in,
                              void* d_out, int out_size, void* d_ws, size_t ws_size,
                              hipStream_t stream) {
    const float* x    = (const float*)d_in[0];
    const float* Win  = (const float*)d_in[1];
    const float* Wdw  = (const float*)d_in[2];
    const float* ff   = (const float*)d_in[3];
    const float* Wout = (const float*)d_in[4];
    float* out = (float*)d_out;
    float* ws  = (float*)d_ws;
    float* zbuf = ws + OFF_Z;

    hipLaunchKernelGGL(k_prep_k, dim3(ICP), dim3(64), 0, stream, ff, ws);
    hipLaunchKernelGGL(k_prep_w, dim3(96), dim3(256), 0, stream, Win, Wdw, Wout, ws);

    // Adaptive z-chunking: chunk of R patch rows needs (R+2, capped 32) rows.
    size_t capf = ws_size / sizeof(float);
    capf = (capf > OFF_Z) ? capf - OFF_Z : 0;
    const size_t perRow = (size_t)C2 * 2048;
    int R;
    if (capf >= perRow * 32) {
        R = 32;
    } else {
        long t = (long)(capf / perRow) - 2;
        R = (t < 1) ? 1 : (t > 32 ? 32 : (int)t);
    }

    for (int b = 0; b < 4; ++b) {
        for (int pr = 0; pr < 32; pr += R) {
            int tr1 = (pr + R < 32) ? pr + R : 32;
            int pr0h = (pr > 0) ? pr - 1 : 0;
            int pr1h = (tr1 < 32) ? tr1 + 1 : 32;
            int nrh = pr1h - pr0h;
            int ntr = tr1 - pr;
            hipLaunchKernelGGL(k_proj_conv, dim3(nrh * 32), dim3(384), 0, stream,
                               x, ws, zbuf, b, pr0h, nrh);
            hipLaunchKernelGGL(k_post, dim3(ntr * 32), dim3(256), 0, stream,
                               zbuf, ws, out, b, pr, pr0h, nrh);
        }
    }
}

// Round 3
// 1342.436 us; speedup vs baseline: 1.5820x; 1.5820x over previous
//
#include <hip/hip_runtime.h>
#include <math.h>

#define DIMC 64
#define C2 340
#define HID 170
#define IMG 256
#define HW 65536          // 256*256
#define ICP 384           // channels padded to 6*64

// ws float offsets (weights area), z chunk buffer follows
#define OFF_WT  0          // Wt[384 ic][64 in]  (= W_in[o(ic)][in], zero pad)     24576 f
#define OFF_KT  24576      // Kt[384 ic][64 d]   (= K_{o(ic)}[d1*8+d2], zero pad)  24576 f
#define OFF_WDI 49152      // wdwI[9 t][340 ic] interleaved depthwise weights       3060 f
#define OFF_WOT 52212      // WoutT[192 c][64 o] (rows >=170 zero)                 12288 f
#define OFF_Z   64500      // z chunk: [nrh*8*256 pix][340 ic] floats (adaptive)

// interleaved channel position: orig o<170 -> 2o ; o>=170 -> 2(o-170)+1
__device__ __forceinline__ int ipos(int o) { return (o < HID) ? (o << 1) : (((o - HID) << 1) + 1); }

// ---------------------------------------------------------------------------
// K_c[d1][d2] = (1/64) sum_{k1<8,k2<5} a(k2)*F[c][k1][k2]*cos(2pi(k1 d1+k2 d2)/8),
// a=1 for k2 in {0,4} else 2.  (rfft2 -> *realF -> irfft2 == circular conv by K.)
// Stored lane-major by interleaved channel: Kt[ic][d].
// ---------------------------------------------------------------------------
__global__ void k_prep_k(const float* __restrict__ f, float* __restrict__ ws) {
    __shared__ float ct[8];
    int c = blockIdx.x;      // 0..383 (>=340 writes zero pad)
    int d = threadIdx.x;     // 0..63
    if (d < 8) {
        const float S = 0.70710678118654752440f;
        float v;
        switch (d) {
            case 0: v = 1.f; break;
            case 1: v = S; break;
            case 2: v = 0.f; break;
            case 3: v = -S; break;
            case 4: v = -1.f; break;
            case 5: v = -S; break;
            case 6: v = 0.f; break;
            default: v = S; break;
        }
        ct[d] = v;
    }
    __syncthreads();
    if (c >= C2) {
        ws[OFF_KT + (size_t)c * 64 + d] = 0.f;
        return;
    }
    int d1 = d >> 3, d2 = d & 7;
    float acc = 0.f;
    #pragma unroll
    for (int k1 = 0; k1 < 8; ++k1) {
        #pragma unroll
        for (int k2 = 0; k2 < 5; ++k2) {
            float a = (k2 == 0 || k2 == 4) ? 1.f : 2.f;
            acc += a * f[c * 40 + k1 * 5 + k2] * ct[(k1 * d1 + k2 * d2) & 7];
        }
    }
    ws[OFF_KT + (size_t)ipos(c) * 64 + d] = acc * (1.f / 64.f);
}

__global__ void k_prep_w(const float* __restrict__ Win, const float* __restrict__ Wdw,
                         const float* __restrict__ Wout, float* __restrict__ ws) {
    int t = blockIdx.x * 256 + threadIdx.x;      // grid 96*256 = 24576
    if (t < ICP * 64) {              // Wt[ic][in]
        int ic = t >> 6, in = t & 63;
        float v = 0.f;
        if (ic < C2) {
            int o = (ic & 1) ? ((ic >> 1) + HID) : (ic >> 1);
            v = Win[o * DIMC + in];
        }
        ws[OFF_WT + (size_t)t] = v;
    }
    if (t < 9 * C2) {                // wdwI (interleaved depthwise weights)
        int tt = t / C2, ic = t % C2;
        int o = (ic & 1) ? ((ic >> 1) + HID) : (ic >> 1);
        ws[OFF_WDI + tt * C2 + ic] = Wdw[o * 9 + tt];
    }
    if (t < 192 * 64) {              // WoutT (zero-padded to 192 rows)
        int c = t >> 6, o = t & 63;
        ws[OFF_WOT + t] = (c < HID) ? Wout[o * HID + c] : 0.f;
    }
}

// ---------------------------------------------------------------------------
// Fused project_in + per-channel 8x8 circular conv.  One block per patch,
// 6 waves x 64 interleaved channels; lane = channel.
//   - x patch read via WAVE-UNIFORM scalar loads (constant cache, SGPR
//     operand to v_fmac) -> zero LDS traffic, zero vector loads for x
//   - projection accumulates p[64 pix] in VGPRs
//   - circular conv fully register-resident (K[64] per lane)
//   - z stores coalesced: pixel-major z[pix][ic], lanes cover contiguous 256B
// ---------------------------------------------------------------------------
__global__ __launch_bounds__(384, 2) void k_proj_conv(const float* __restrict__ x,
                                                      const float* __restrict__ ws,
                                                      float* __restrict__ z,
                                                      int b, int pr0, int nr) {
    int blk = blockIdx.x;
    int pyl = blk >> 5, px = blk & 31;
    int py = pr0 + pyl;
    int tid = threadIdx.x;
    int ic = tid;                            // interleaved channel, 0..383
    bool icv = ic < C2;

    // wave-uniform x patch base (block-derived only)
    const float* xb = x + (size_t)b * DIMC * HW + (size_t)(py * 8) * IMG + px * 8;

    // projection: p[pix] = sum_in Wt[ic][in] * x[in][pix]
    float p[64];
    #pragma unroll
    for (int i = 0; i < 64; ++i) p[i] = 0.f;
    const float4* Wq = (const float4*)(ws + OFF_WT) + (size_t)ic * 16;
    for (int q = 0; q < 16; ++q) {           // 4 input channels per iter
        float4 wv = Wq[q];                   // per-lane, L2-resident
        const float* xr0 = xb + (size_t)(q * 4) * HW;
        #pragma unroll
        for (int j = 0; j < 4; ++j) {
            const float* xr = xr0 + (size_t)j * HW;   // uniform
            float wj = (j == 0) ? wv.x : (j == 1) ? wv.y : (j == 2) ? wv.z : wv.w;
            #pragma unroll
            for (int r = 0; r < 8; ++r) {
                #pragma unroll
                for (int cx = 0; cx < 8; ++cx) {
                    p[r * 8 + cx] += wj * xr[r * IMG + cx];  // uniform scalar load
                }
            }
        }
    }

    // load this lane's circular-conv kernel K[64]
    float K[64];
    const float4* Kq = (const float4*)(ws + OFF_KT) + (size_t)ic * 16;
    #pragma unroll
    for (int q = 0; q < 16; ++q) {
        float4 kv = Kq[q];
        K[q * 4 + 0] = kv.x; K[q * 4 + 1] = kv.y;
        K[q * 4 + 2] = kv.z; K[q * 4 + 3] = kv.w;
    }

    // circular 8x8 conv, all in registers; store row-by-row (coalesced over ic)
    #pragma unroll
    for (int d1 = 0; d1 < 8; ++d1) {
        float zr[8];
        #pragma unroll
        for (int i = 0; i < 8; ++i) zr[i] = 0.f;
        #pragma unroll
        for (int e1 = 0; e1 < 8; ++e1) {
            const int r1 = (d1 - e1) & 7;
            #pragma unroll
            for (int e2 = 0; e2 < 8; ++e2) {
                float pv = p[e1 * 8 + e2];
                #pragma unroll
                for (int d2 = 0; d2 < 8; ++d2)
                    zr[d2] += K[r1 * 8 + ((d2 - e2) & 7)] * pv;
            }
        }
        if (icv) {
            float* zp = z + ((size_t)((pyl * 8 + d1) * IMG + px * 8)) * C2 + ic;
            #pragma unroll
            for (int d2 = 0; d2 < 8; ++d2) zp[(size_t)d2 * C2] = zr[d2];
        }
    }
}

// ---------------------------------------------------------------------------
// Fused depthwise 3x3 (zero pad) + exact GELU-GLU + project_out GEMM.
// Per 64-ic group: stage 10x10 halo to LDS (coalesced float4), depthwise from
// LDS with register rolling (lane=ic, conflict-free), GLU via shfl_xor(1),
// then IMMEDIATE partial project_out over the group's 32 o-channels (acc[16]
// persists) -> no big gbuf, LDS 33.9 KB -> 4 blocks/CU.
// ---------------------------------------------------------------------------
__device__ __forceinline__ float gelu_exact(float v) {
    return 0.5f * v * (1.f + erff(v * 0.70710678118654752440f));
}

__global__ __launch_bounds__(256) void k_post(const float* __restrict__ z,
                                              const float* __restrict__ ws,
                                              float* __restrict__ out,
                                              int b, int tr0, int pr0h, int nrh) {
    __shared__ float zs[100 * 64];       // 10x10 halo x 64 ch, 25.6 KB
    __shared__ float gsl[32 * 65];       // group GLU slab, 8.3 KB
    int blk = blockIdx.x;
    int ty = tr0 + (blk >> 5), tx = blk & 31;
    int tid = threadIdx.x;
    int w = tid >> 6, lane = tid & 63;
    int gy0 = ty * 8, gx0 = tx * 8;
    int ybase = pr0h * 8;

    float acc[16];                        // project_out partials, lane = pixel
    #pragma unroll
    for (int k = 0; k < 16; ++k) acc[k] = 0.f;
    int ob = __builtin_amdgcn_readfirstlane(w * 16);

    for (int g = 0; g < 6; ++g) {
        int ic0 = g << 6;
        int ic = ic0 + lane;
        bool icv = ic < C2;

        __syncthreads();                  // zs/gsl free from previous group
        // --- stage 10x10 halo x 64 ch (coalesced 16B/lane) ---
        for (int u = tid; u < 1600; u += 256) {
            int pp = u >> 4;              // position 0..99
            int ch4 = (u & 15) << 2;
            int py_ = gy0 - 1 + pp / 10;
            int px_ = gx0 - 1 + pp % 10;
            float4 v = make_float4(0.f, 0.f, 0.f, 0.f);
            if ((unsigned)py_ < (unsigned)IMG && (unsigned)px_ < (unsigned)IMG &&
                (ic0 + ch4) < C2)
                v = *(const float4*)(z + ((size_t)(py_ - ybase) * IMG + px_) * C2
                                       + ic0 + ch4);
            *(float4*)&zs[pp * 64 + ch4] = v;
        }
        __syncthreads();

        // --- depthwise 3x3 + GELU-GLU; wave w -> output rows 2w, 2w+1 ---
        float wt[9];
        #pragma unroll
        for (int t = 0; t < 9; ++t)
            wt[t] = icv ? ws[OFF_WDI + t * C2 + ic] : 0.f;

        int oy0 = w * 2;
        float rr[4][10];                  // rolling rows, conflict-free ds_read
        #pragma unroll
        for (int rrow = 0; rrow < 4; ++rrow)
            #pragma unroll
            for (int cc = 0; cc < 10; ++cc)
                rr[rrow][cc] = zs[((oy0 + rrow) * 10 + cc) * 64 + lane];

        #pragma unroll
        for (int ry = 0; ry < 2; ++ry) {
            #pragma unroll
            for (int ox = 0; ox < 8; ++ox) {
                float a = wt[0] * rr[ry][ox]     + wt[1] * rr[ry][ox + 1]     + wt[2] * rr[ry][ox + 2]
                        + wt[3] * rr[ry + 1][ox] + wt[4] * rr[ry + 1][ox + 1] + wt[5] * rr[ry + 1][ox + 2]
                        + wt[6] * rr[ry + 2][ox] + wt[7] * rr[ry + 2][ox + 1] + wt[8] * rr[ry + 2][ox + 2];
                float prt = __shfl_xor(a, 1);     // partner (dw2) value
                if (!(lane & 1))                  // even lane owns o' = lane>>1
                    gsl[(lane >> 1) * 65 + (oy0 + ry) * 8 + ox] =
                        icv ? (gelu_exact(a) * prt) : 0.f;
            }
        }
        __syncthreads();

        // --- partial project_out over this group's 32 o-channels ---
        int yy = gy0 + (lane >> 3), xx = gx0 + (lane & 7);
        (void)yy; (void)xx;
        const float* wb = ws + OFF_WOT + (size_t)(g * 32) * 64 + ob;  // uniform
        #pragma unroll
        for (int cp = 0; cp < 32; ++cp) {
            float gv = gsl[cp * 65 + lane];
            const float* wp = wb + cp * 64;       // rows >=170 are zeros
            #pragma unroll
            for (int k = 0; k < 16; ++k) acc[k] += wp[k] * gv;
        }
    }

    int yy = gy0 + (lane >> 3), xx = gx0 + (lane & 7);
    #pragma unroll
    for (int k = 0; k < 16; ++k)
        out[((size_t)b * 64 + ob + k) * HW + (size_t)yy * IMG + xx] = acc[k];
}

// ---------------------------------------------------------------------------
extern "C" void kernel_launch(void* const* d_in, const int* in_sizes, int n_in,
                              void* d_out, int out_size, void* d_ws, size_t ws_size,
                              hipStream_t stream) {
    const float* x    = (const float*)d_in[0];
    const float* Win  = (const float*)d_in[1];
    const float* Wdw  = (const float*)d_in[2];
    const float* ff   = (const float*)d_in[3];
    const float* Wout = (const float*)d_in[4];
    float* out = (float*)d_out;
    float* ws  = (float*)d_ws;
    float* zbuf = ws + OFF_Z;

    hipLaunchKernelGGL(k_prep_k, dim3(ICP), dim3(64), 0, stream, ff, ws);
    hipLaunchKernelGGL(k_prep_w, dim3(96), dim3(256), 0, stream, Win, Wdw, Wout, ws);

    // Adaptive z-chunking: chunk of R patch rows needs (R+2, capped 32) rows.
    size_t capf = ws_size / sizeof(float);
    capf = (capf > OFF_Z) ? capf - OFF_Z : 0;
    const size_t perRow = (size_t)C2 * 2048;
    int R;
    if (capf >= perRow * 32) {
        R = 32;
    } else {
        long t = (long)(capf / perRow) - 2;
        R = (t < 1) ? 1 : (t > 32 ? 32 : (int)t);
    }

    for (int b = 0; b < 4; ++b) {
        for (int pr = 0; pr < 32; pr += R) {
            int tr1 = (pr + R < 32) ? pr + R : 32;
            int pr0h = (pr > 0) ? pr - 1 : 0;
            int pr1h = (tr1 < 32) ? tr1 + 1 : 32;
            int nrh = pr1h - pr0h;
            int ntr = tr1 - pr;
            hipLaunchKernelGGL(k_proj_conv, dim3(nrh * 32), dim3(384), 0, stream,
                               x, ws, zbuf, b, pr0h, nrh);
            hipLaunchKernelGGL(k_post, dim3(ntr * 32), dim3(256), 0, stream,
                               zbuf, ws, out, b, pr, pr0h, nrh);
        }
    }
}

// Round 6
// 966.021 us; speedup vs baseline: 2.1985x; 1.3897x over previous
//
#include <hip/hip_runtime.h>
#include <math.h>

#define DIMC 64
#define C2 340
#define HID 170
#define IMG 256
#define HW 65536          // 256*256
#define ICP 384           // channels padded to 6*64

// ws float offsets (weights area), z chunk buffer follows
#define OFF_WT  0          // Wt[384 ic][64 in]  (= W_in[o(ic)][in], zero pad)     24576 f
#define OFF_KT  24576      // KT[64 d][384 ic]   TRANSPOSED, cols >=340 zero       24576 f
#define OFF_WDI 49152      // wdwI[9 t][340 ic] interleaved depthwise weights       3060 f
#define OFF_WOT 52212      // WoutT[192 c][64 o] (rows >=170 zero)                 12288 f
#define OFF_Z   64500      // z chunk: [nrh*8*256 pix][340 ic] floats (adaptive)

// interleaved channel position: orig o<170 -> 2o ; o>=170 -> 2(o-170)+1
__device__ __forceinline__ int ipos(int o) { return (o < HID) ? (o << 1) : (((o - HID) << 1) + 1); }

// ---------------------------------------------------------------------------
// K_c[d1][d2] = (1/64) sum_{k1<8,k2<5} a(k2)*F[c][k1][k2]*cos(2pi(k1 d1+k2 d2)/8),
// a=1 for k2 in {0,4} else 2.  (rfft2 -> *realF -> irfft2 == circular conv by K.)
// Stored TRANSPOSED: KT[d][ic] so lane=ic kernel loads are coalesced.
// ---------------------------------------------------------------------------
__global__ void k_prep_k(const float* __restrict__ f, float* __restrict__ ws) {
    __shared__ float ct[8];
    int c = blockIdx.x;      // 0..383 (>=340 zeros the pad columns)
    int d = threadIdx.x;     // 0..63
    if (d < 8) {
        const float S = 0.70710678118654752440f;
        float v;
        switch (d) {
            case 0: v = 1.f; break;
            case 1: v = S; break;
            case 2: v = 0.f; break;
            case 3: v = -S; break;
            case 4: v = -1.f; break;
            case 5: v = -S; break;
            case 6: v = 0.f; break;
            default: v = S; break;
        }
        ct[d] = v;
    }
    __syncthreads();
    if (c >= C2) {           // pad column (ipos never maps here)
        ws[OFF_KT + (size_t)d * ICP + c] = 0.f;
        return;
    }
    int d1 = d >> 3, d2 = d & 7;
    float acc = 0.f;
    #pragma unroll
    for (int k1 = 0; k1 < 8; ++k1) {
        #pragma unroll
        for (int k2 = 0; k2 < 5; ++k2) {
            float a = (k2 == 0 || k2 == 4) ? 1.f : 2.f;
            acc += a * f[c * 40 + k1 * 5 + k2] * ct[(k1 * d1 + k2 * d2) & 7];
        }
    }
    ws[OFF_KT + (size_t)d * ICP + ipos(c)] = acc * (1.f / 64.f);
}

__global__ void k_prep_w(const float* __restrict__ Win, const float* __restrict__ Wdw,
                         const float* __restrict__ Wout, float* __restrict__ ws) {
    int t = blockIdx.x * 256 + threadIdx.x;      // grid 96*256 = 24576
    if (t < ICP * 64) {              // Wt[ic][in]
        int ic = t >> 6, in = t & 63;
        float v = 0.f;
        if (ic < C2) {
            int o = (ic & 1) ? ((ic >> 1) + HID) : (ic >> 1);
            v = Win[o * DIMC + in];
        }
        ws[OFF_WT + (size_t)t] = v;
    }
    if (t < 9 * C2) {                // wdwI (interleaved depthwise weights)
        int tt = t / C2, ic = t % C2;
        int o = (ic & 1) ? ((ic >> 1) + HID) : (ic >> 1);
        ws[OFF_WDI + tt * C2 + ic] = Wdw[o * 9 + tt];
    }
    if (t < 192 * 64) {              // WoutT (zero-padded to 192 rows)
        int c = t >> 6, o = t & 63;
        ws[OFF_WOT + t] = (c < HID) ? Wout[o * HID + c] : 0.f;
    }
}

// ---------------------------------------------------------------------------
// Fused project_in + per-channel 8x8 circular conv.  One block per patch,
// 6 waves x 64 interleaved channels; lane = channel.
//   - x patch staged to LDS [in][pix]; read as wave-uniform b128 broadcasts
//   - projection accumulates p[64 pix] in VGPRs (static indices)
//   - conv is PREPROCESSOR-EXPANDED: 4096 FMAs with literal indices, K
//     streamed one element at a time (coalesced L2 load right before its
//     64 FMAs) -> p[64]+za[64] static SSA, no dynamic array access possible
//   - z stores coalesced: pixel-major z[pix][ic], lanes cover contiguous 256B
// ---------------------------------------------------------------------------

// za[d1][d2] += K[t1][t2] * p[(d1-t1)&7][(d2-t2)&7]  (all indices literal)
#define F1(t1,t2,d1,d2) za[(d1)*8+(d2)] += kv * p[((((d1)+8-(t1))&7)<<3) + (((d2)+8-(t2))&7)];
#define FR8(t1,t2,d1) F1(t1,t2,d1,0) F1(t1,t2,d1,1) F1(t1,t2,d1,2) F1(t1,t2,d1,3) \
                      F1(t1,t2,d1,4) F1(t1,t2,d1,5) F1(t1,t2,d1,6) F1(t1,t2,d1,7)
#define FT(t1,t2) { const float kv = KTb[(size_t)((t1)*8+(t2)) * ICP]; \
                    FR8(t1,t2,0) FR8(t1,t2,1) FR8(t1,t2,2) FR8(t1,t2,3) \
                    FR8(t1,t2,4) FR8(t1,t2,5) FR8(t1,t2,6) FR8(t1,t2,7) }
#define FTROW(t1) FT(t1,0) FT(t1,1) FT(t1,2) FT(t1,3) FT(t1,4) FT(t1,5) FT(t1,6) FT(t1,7)

__global__ __launch_bounds__(384, 3) void k_proj_conv(const float* __restrict__ x,
                                                      const float* __restrict__ ws,
                                                      float* __restrict__ z,
                                                      int b, int pr0, int nr) {
    __shared__ float xs[64 * 64];            // [in][pix] 16 KB
    int blk = blockIdx.x;
    int pyl = blk >> 5, px = blk & 31;
    int py = pr0 + pyl;
    int tid = threadIdx.x;
    int ic = tid;                            // interleaved channel, 0..383
    bool icv = ic < C2;

    // stage x patch  [in][8x8] -> xs[in][pix]
    const float* xb = x + (size_t)b * DIMC * HW + (size_t)(py * 8) * IMG + px * 8;
    for (int u = tid; u < 1024; u += 384) {
        int in = u >> 4, rem = u & 15;
        int r = rem >> 1, h = rem & 1;
        *(float4*)&xs[in * 64 + r * 8 + h * 4] =
            *(const float4*)(xb + (size_t)in * HW + r * IMG + h * 4);
    }
    __syncthreads();

    // projection: p[pix] = sum_in Wt[ic][in] * xs[in][pix]
    float p[64];
    #pragma unroll
    for (int i = 0; i < 64; ++i) p[i] = 0.f;
    const float4* Wq = (const float4*)(ws + OFF_WT) + (size_t)ic * 16;
    for (int q = 0; q < 16; ++q) {
        float4 wv = Wq[q];                    // per-lane, L2-resident
        float wj[4] = {wv.x, wv.y, wv.z, wv.w};
        #pragma unroll
        for (int j = 0; j < 4; ++j) {
            const float4* xr = (const float4*)(xs + (q * 4 + j) * 64);
            #pragma unroll
            for (int pq = 0; pq < 16; ++pq) {
                float4 xv = xr[pq];           // wave-uniform broadcast
                p[pq * 4 + 0] += wj[j] * xv.x;
                p[pq * 4 + 1] += wj[j] * xv.y;
                p[pq * 4 + 2] += wj[j] * xv.z;
                p[pq * 4 + 3] += wj[j] * xv.w;
            }
        }
    }

    // circular 8x8 conv, macro-expanded; K streamed element-wise (coalesced)
    float za[64];
    #pragma unroll
    for (int i = 0; i < 64; ++i) za[i] = 0.f;
    const float* KTb = ws + OFF_KT + ic;      // KT[d][ic], lane-consecutive
    FTROW(0) FTROW(1) FTROW(2) FTROW(3) FTROW(4) FTROW(5) FTROW(6) FTROW(7)

    // store row-by-row (coalesced over ic)
    if (icv) {
        #pragma unroll
        for (int d1 = 0; d1 < 8; ++d1) {
            float* zp = z + ((size_t)((pyl * 8 + d1) * IMG + px * 8)) * C2 + ic;
            #pragma unroll
            for (int d2 = 0; d2 < 8; ++d2) zp[(size_t)d2 * C2] = za[d1 * 8 + d2];
        }
    }
}

// ---------------------------------------------------------------------------
// Fused depthwise 3x3 (zero pad) + exact GELU-GLU + project_out GEMM.
// Per 64-ic group: stage 10x10 halo to LDS (coalesced float4), depthwise from
// LDS with register rolling (lane=ic, conflict-free), GLU via shfl_xor(1),
// then IMMEDIATE partial project_out over the group's 32 o-channels (acc[16]
// persists) -> no big gbuf, LDS 33.9 KB -> 4 blocks/CU.
// ---------------------------------------------------------------------------
__device__ __forceinline__ float gelu_exact(float v) {
    return 0.5f * v * (1.f + erff(v * 0.70710678118654752440f));
}

__global__ __launch_bounds__(256) void k_post(const float* __restrict__ z,
                                              const float* __restrict__ ws,
                                              float* __restrict__ out,
                                              int b, int tr0, int pr0h, int nrh) {
    __shared__ float zs[100 * 64];       // 10x10 halo x 64 ch, 25.6 KB
    __shared__ float gsl[32 * 65];       // group GLU slab, 8.3 KB
    int blk = blockIdx.x;
    int ty = tr0 + (blk >> 5), tx = blk & 31;
    int tid = threadIdx.x;
    int w = tid >> 6, lane = tid & 63;
    int gy0 = ty * 8, gx0 = tx * 8;
    int ybase = pr0h * 8;

    float acc[16];                        // project_out partials, lane = pixel
    #pragma unroll
    for (int k = 0; k < 16; ++k) acc[k] = 0.f;
    int ob = __builtin_amdgcn_readfirstlane(w * 16);

    for (int g = 0; g < 6; ++g) {
        int ic0 = g << 6;
        int ic = ic0 + lane;
        bool icv = ic < C2;

        __syncthreads();                  // zs/gsl free from previous group
        // --- stage 10x10 halo x 64 ch (coalesced 16B/lane) ---
        for (int u = tid; u < 1600; u += 256) {
            int pp = u >> 4;              // position 0..99
            int ch4 = (u & 15) << 2;
            int py_ = gy0 - 1 + pp / 10;
            int px_ = gx0 - 1 + pp % 10;
            float4 v = make_float4(0.f, 0.f, 0.f, 0.f);
            if ((unsigned)py_ < (unsigned)IMG && (unsigned)px_ < (unsigned)IMG &&
                (ic0 + ch4) < C2)
                v = *(const float4*)(z + ((size_t)(py_ - ybase) * IMG + px_) * C2
                                       + ic0 + ch4);
            *(float4*)&zs[pp * 64 + ch4] = v;
        }
        __syncthreads();

        // --- depthwise 3x3 + GELU-GLU; wave w -> output rows 2w, 2w+1 ---
        float wt[9];
        #pragma unroll
        for (int t = 0; t < 9; ++t)
            wt[t] = icv ? ws[OFF_WDI + t * C2 + ic] : 0.f;

        int oy0 = w * 2;
        float rr[4][10];                  // rolling rows, conflict-free ds_read
        #pragma unroll
        for (int rrow = 0; rrow < 4; ++rrow)
            #pragma unroll
            for (int cc = 0; cc < 10; ++cc)
                rr[rrow][cc] = zs[((oy0 + rrow) * 10 + cc) * 64 + lane];

        #pragma unroll
        for (int ry = 0; ry < 2; ++ry) {
            #pragma unroll
            for (int ox = 0; ox < 8; ++ox) {
                float a = wt[0] * rr[ry][ox]     + wt[1] * rr[ry][ox + 1]     + wt[2] * rr[ry][ox + 2]
                        + wt[3] * rr[ry + 1][ox] + wt[4] * rr[ry + 1][ox + 1] + wt[5] * rr[ry + 1][ox + 2]
                        + wt[6] * rr[ry + 2][ox] + wt[7] * rr[ry + 2][ox + 1] + wt[8] * rr[ry + 2][ox + 2];
                float prt = __shfl_xor(a, 1);     // partner (dw2) value
                if (!(lane & 1))                  // even lane owns o' = lane>>1
                    gsl[(lane >> 1) * 65 + (oy0 + ry) * 8 + ox] =
                        icv ? (gelu_exact(a) * prt) : 0.f;
            }
        }
        __syncthreads();

        // --- partial project_out over this group's 32 o-channels ---
        const float* wb = ws + OFF_WOT + (size_t)(g * 32) * 64 + ob;  // uniform
        #pragma unroll
        for (int cp = 0; cp < 32; ++cp) {
            float gv = gsl[cp * 65 + lane];
            const float* wp = wb + cp * 64;       // rows >=170 are zeros
            #pragma unroll
            for (int k = 0; k < 16; ++k) acc[k] += wp[k] * gv;
        }
    }

    int yy = gy0 + (lane >> 3), xx = gx0 + (lane & 7);
    #pragma unroll
    for (int k = 0; k < 16; ++k)
        out[((size_t)b * 64 + ob + k) * HW + (size_t)yy * IMG + xx] = acc[k];
}

// ---------------------------------------------------------------------------
extern "C" void kernel_launch(void* const* d_in, const int* in_sizes, int n_in,
                              void* d_out, int out_size, void* d_ws, size_t ws_size,
                              hipStream_t stream) {
    const float* x    = (const float*)d_in[0];
    const float* Win  = (const float*)d_in[1];
    const float* Wdw  = (const float*)d_in[2];
    const float* ff   = (const float*)d_in[3];
    const float* Wout = (const float*)d_in[4];
    float* out = (float*)d_out;
    float* ws  = (float*)d_ws;
    float* zbuf = ws + OFF_Z;

    hipLaunchKernelGGL(k_prep_k, dim3(ICP), dim3(64), 0, stream, ff, ws);
    hipLaunchKernelGGL(k_prep_w, dim3(96), dim3(256), 0, stream, Win, Wdw, Wout, ws);

    // Adaptive z-chunking: chunk of R patch rows needs (R+2, capped 32) rows.
    size_t capf = ws_size / sizeof(float);
    capf = (capf > OFF_Z) ? capf - OFF_Z : 0;
    const size_t perRow = (size_t)C2 * 2048;
    int R;
    if (capf >= perRow * 32) {
        R = 32;
    } else {
        long t = (long)(capf / perRow) - 2;
        R = (t < 1) ? 1 : (t > 32 ? 32 : (int)t);
    }

    for (int b = 0; b < 4; ++b) {
        for (int pr = 0; pr < 32; pr += R) {
            int tr1 = (pr + R < 32) ? pr + R : 32;
            int pr0h = (pr > 0) ? pr - 1 : 0;
            int pr1h = (tr1 < 32) ? tr1 + 1 : 32;
            int nrh = pr1h - pr0h;
            int ntr = tr1 - pr;
            hipLaunchKernelGGL(k_proj_conv, dim3(nrh * 32), dim3(384), 0, stream,
                               x, ws, zbuf, b, pr0h, nrh);
            hipLaunchKernelGGL(k_post, dim3(ntr * 32), dim3(256), 0, stream,
                               zbuf, ws, out, b, pr, pr0h, nrh);
        }
    }
}

// Round 7
// 947.424 us; speedup vs baseline: 2.2416x; 1.0196x over previous
//
#include <hip/hip_runtime.h>
#include <math.h>

#define DIMC 64
#define C2 340
#define HID 170
#define IMG 256
#define HW 65536          // 256*256
#define ICP 384           // channels padded to 6*64

// ws float offsets (weights area), z chunk buffer follows
#define OFF_WT  0          // Wt[384 ic][64 in]  (= W_in[o(ic)][in], zero pad)     24576 f
#define OFF_KT  24576      // KT[64 d][384 ic]   TRANSPOSED, cols >=340 zero       24576 f
#define OFF_WDI 49152      // wdwI[9 t][340 ic] interleaved depthwise weights       3060 f
#define OFF_WOT 52212      // WoutT[192 c][64 o] (rows >=170 zero)                 12288 f
#define OFF_Z   64500      // z chunk: [nrh*8*256 pix][340 ic] floats (adaptive)

// interleaved channel position: orig o<170 -> 2o ; o>=170 -> 2(o-170)+1
__device__ __forceinline__ int ipos(int o) { return (o < HID) ? (o << 1) : (((o - HID) << 1) + 1); }

// ---------------------------------------------------------------------------
// K_c[d1][d2] = (1/64) sum_{k1<8,k2<5} a(k2)*F[c][k1][k2]*cos(2pi(k1 d1+k2 d2)/8),
// a=1 for k2 in {0,4} else 2.  (rfft2 -> *realF -> irfft2 == circular conv by K.)
// Stored TRANSPOSED: KT[d][ic] so lane=ic kernel loads are coalesced.
// ---------------------------------------------------------------------------
__global__ void k_prep_k(const float* __restrict__ f, float* __restrict__ ws) {
    __shared__ float ct[8];
    int c = blockIdx.x;      // 0..383 (>=340 zeros the pad columns)
    int d = threadIdx.x;     // 0..63
    if (d < 8) {
        const float S = 0.70710678118654752440f;
        float v;
        switch (d) {
            case 0: v = 1.f; break;
            case 1: v = S; break;
            case 2: v = 0.f; break;
            case 3: v = -S; break;
            case 4: v = -1.f; break;
            case 5: v = -S; break;
            case 6: v = 0.f; break;
            default: v = S; break;
        }
        ct[d] = v;
    }
    __syncthreads();
    if (c >= C2) {           // pad column (ipos never maps here)
        ws[OFF_KT + (size_t)d * ICP + c] = 0.f;
        return;
    }
    int d1 = d >> 3, d2 = d & 7;
    float acc = 0.f;
    #pragma unroll
    for (int k1 = 0; k1 < 8; ++k1) {
        #pragma unroll
        for (int k2 = 0; k2 < 5; ++k2) {
            float a = (k2 == 0 || k2 == 4) ? 1.f : 2.f;
            acc += a * f[c * 40 + k1 * 5 + k2] * ct[(k1 * d1 + k2 * d2) & 7];
        }
    }
    ws[OFF_KT + (size_t)d * ICP + ipos(c)] = acc * (1.f / 64.f);
}

__global__ void k_prep_w(const float* __restrict__ Win, const float* __restrict__ Wdw,
                         const float* __restrict__ Wout, float* __restrict__ ws) {
    int t = blockIdx.x * 256 + threadIdx.x;      // grid 96*256 = 24576
    if (t < ICP * 64) {              // Wt[ic][in]
        int ic = t >> 6, in = t & 63;
        float v = 0.f;
        if (ic < C2) {
            int o = (ic & 1) ? ((ic >> 1) + HID) : (ic >> 1);
            v = Win[o * DIMC + in];
        }
        ws[OFF_WT + (size_t)t] = v;
    }
    if (t < 9 * C2) {                // wdwI (interleaved depthwise weights)
        int tt = t / C2, ic = t % C2;
        int o = (ic & 1) ? ((ic >> 1) + HID) : (ic >> 1);
        ws[OFF_WDI + tt * C2 + ic] = Wdw[o * 9 + tt];
    }
    if (t < 192 * 64) {              // WoutT (zero-padded to 192 rows)
        int c = t >> 6, o = t & 63;
        ws[OFF_WOT + t] = (c < HID) ? Wout[o * HID + c] : 0.f;
    }
}

// ---------------------------------------------------------------------------
// Fused project_in + per-channel 8x8 circular conv.  One block per patch,
// 6 waves x 64 interleaved channels; lane = channel.
//   - x patch staged to LDS [in][pix]; read as wave-uniform b128 broadcasts
//   - projection accumulates p[64 pix] in VGPRs (static indices)
//   - conv streamed TWO OUTPUT ROWS per pass (4 passes): zr[16] live, all
//     64 K taps re-streamed per pass (coalesced L2 loads), rows stored
//     immediately.  Live set ~90 VGPR -> no spill (round-6 spilled at 84).
//   - amdgpu_waves_per_eu(3,4): RA has no incentive to squeeze below 128
//   - z stores coalesced: pixel-major z[pix][ic], lanes cover contiguous 256B
// ---------------------------------------------------------------------------

// zr[rr][d2] += K[t1][t2] * p[(2*PS+rr-t1)&7][(d2-t2)&7]   (all literal)
#define G1(PS,t1,t2,rr,d2) zr[(rr)*8+(d2)] += kv * p[((((2*(PS))+(rr)+8-(t1))&7)<<3) + (((d2)+8-(t2))&7)];
#define GR8(PS,t1,t2,rr) G1(PS,t1,t2,rr,0) G1(PS,t1,t2,rr,1) G1(PS,t1,t2,rr,2) G1(PS,t1,t2,rr,3) \
                         G1(PS,t1,t2,rr,4) G1(PS,t1,t2,rr,5) G1(PS,t1,t2,rr,6) G1(PS,t1,t2,rr,7)
#define GT(PS,t1,t2) { const float kv = KTb[(size_t)((t1)*8+(t2)) * ICP]; \
                       GR8(PS,t1,t2,0) GR8(PS,t1,t2,1) }
#define GTROW(PS,t1) GT(PS,t1,0) GT(PS,t1,1) GT(PS,t1,2) GT(PS,t1,3) \
                     GT(PS,t1,4) GT(PS,t1,5) GT(PS,t1,6) GT(PS,t1,7)
#define ZST(ZP,OF) (ZP)[0]=zr[(OF)+0]; (ZP)[(size_t)1*C2]=zr[(OF)+1]; (ZP)[(size_t)2*C2]=zr[(OF)+2]; \
                   (ZP)[(size_t)3*C2]=zr[(OF)+3]; (ZP)[(size_t)4*C2]=zr[(OF)+4]; (ZP)[(size_t)5*C2]=zr[(OF)+5]; \
                   (ZP)[(size_t)6*C2]=zr[(OF)+6]; (ZP)[(size_t)7*C2]=zr[(OF)+7];
#define GPASS(PS) { \
    float zr[16]; \
    zr[0]=0.f; zr[1]=0.f; zr[2]=0.f; zr[3]=0.f; zr[4]=0.f; zr[5]=0.f; zr[6]=0.f; zr[7]=0.f; \
    zr[8]=0.f; zr[9]=0.f; zr[10]=0.f; zr[11]=0.f; zr[12]=0.f; zr[13]=0.f; zr[14]=0.f; zr[15]=0.f; \
    GTROW(PS,0) GTROW(PS,1) GTROW(PS,2) GTROW(PS,3) GTROW(PS,4) GTROW(PS,5) GTROW(PS,6) GTROW(PS,7) \
    if (icv) { \
        float* zp0 = z + ((size_t)((pyl * 8 + 2*(PS)) * IMG + px * 8)) * C2 + ic; \
        float* zp1 = z + ((size_t)((pyl * 8 + 2*(PS) + 1) * IMG + px * 8)) * C2 + ic; \
        ZST(zp0,0) ZST(zp1,8) \
    } \
}

__global__ __launch_bounds__(384)
__attribute__((amdgpu_waves_per_eu(3, 4)))
void k_proj_conv(const float* __restrict__ x,
                 const float* __restrict__ ws,
                 float* __restrict__ z,
                 int b, int pr0, int nr) {
    __shared__ float xs[64 * 64];            // [in][pix] 16 KB
    int blk = blockIdx.x;
    int pyl = blk >> 5, px = blk & 31;
    int py = pr0 + pyl;
    int tid = threadIdx.x;
    int ic = tid;                            // interleaved channel, 0..383
    bool icv = ic < C2;

    // stage x patch  [in][8x8] -> xs[in][pix]
    const float* xb = x + (size_t)b * DIMC * HW + (size_t)(py * 8) * IMG + px * 8;
    for (int u = tid; u < 1024; u += 384) {
        int in = u >> 4, rem = u & 15;
        int r = rem >> 1, h = rem & 1;
        *(float4*)&xs[in * 64 + r * 8 + h * 4] =
            *(const float4*)(xb + (size_t)in * HW + r * IMG + h * 4);
    }
    __syncthreads();

    // projection: p[pix] = sum_in Wt[ic][in] * xs[in][pix]
    float p[64];
    #pragma unroll
    for (int i = 0; i < 64; ++i) p[i] = 0.f;
    const float4* Wq = (const float4*)(ws + OFF_WT) + (size_t)ic * 16;
    for (int q = 0; q < 16; ++q) {
        float4 wv = Wq[q];                    // per-lane, L2-resident
        float wj[4] = {wv.x, wv.y, wv.z, wv.w};
        #pragma unroll
        for (int j = 0; j < 4; ++j) {
            const float4* xr = (const float4*)(xs + (q * 4 + j) * 64);
            #pragma unroll
            for (int pq = 0; pq < 16; ++pq) {
                float4 xv = xr[pq];           // wave-uniform broadcast
                p[pq * 4 + 0] += wj[j] * xv.x;
                p[pq * 4 + 1] += wj[j] * xv.y;
                p[pq * 4 + 2] += wj[j] * xv.z;
                p[pq * 4 + 3] += wj[j] * xv.w;
            }
        }
    }

    // circular 8x8 conv: 4 passes x 2 output rows, K streamed per tap
    const float* KTb = ws + OFF_KT + ic;      // KT[d][ic], lane-consecutive
    GPASS(0) GPASS(1) GPASS(2) GPASS(3)
}

// ---------------------------------------------------------------------------
// Fused depthwise 3x3 (zero pad) + exact GELU-GLU + project_out GEMM.
// Per 64-ic group: stage 10x10 halo to LDS (coalesced float4), depthwise from
// LDS with register rolling (lane=ic, conflict-free), GLU via shfl_xor(1),
// then IMMEDIATE partial project_out over the group's 32 o-channels (acc[16]
// persists) -> no big gbuf, LDS 33.9 KB -> 4 blocks/CU.
// ---------------------------------------------------------------------------
__device__ __forceinline__ float gelu_exact(float v) {
    return 0.5f * v * (1.f + erff(v * 0.70710678118654752440f));
}

__global__ __launch_bounds__(256) void k_post(const float* __restrict__ z,
                                              const float* __restrict__ ws,
                                              float* __restrict__ out,
                                              int b, int tr0, int pr0h, int nrh) {
    __shared__ float zs[100 * 64];       // 10x10 halo x 64 ch, 25.6 KB
    __shared__ float gsl[32 * 65];       // group GLU slab, 8.3 KB
    int blk = blockIdx.x;
    int ty = tr0 + (blk >> 5), tx = blk & 31;
    int tid = threadIdx.x;
    int w = tid >> 6, lane = tid & 63;
    int gy0 = ty * 8, gx0 = tx * 8;
    int ybase = pr0h * 8;

    float acc[16];                        // project_out partials, lane = pixel
    #pragma unroll
    for (int k = 0; k < 16; ++k) acc[k] = 0.f;
    int ob = __builtin_amdgcn_readfirstlane(w * 16);

    for (int g = 0; g < 6; ++g) {
        int ic0 = g << 6;
        int ic = ic0 + lane;
        bool icv = ic < C2;

        __syncthreads();                  // zs/gsl free from previous group
        // --- stage 10x10 halo x 64 ch (coalesced 16B/lane) ---
        for (int u = tid; u < 1600; u += 256) {
            int pp = u >> 4;              // position 0..99
            int ch4 = (u & 15) << 2;
            int py_ = gy0 - 1 + pp / 10;
            int px_ = gx0 - 1 + pp % 10;
            float4 v = make_float4(0.f, 0.f, 0.f, 0.f);
            if ((unsigned)py_ < (unsigned)IMG && (unsigned)px_ < (unsigned)IMG &&
                (ic0 + ch4) < C2)
                v = *(const float4*)(z + ((size_t)(py_ - ybase) * IMG + px_) * C2
                                       + ic0 + ch4);
            *(float4*)&zs[pp * 64 + ch4] = v;
        }
        __syncthreads();

        // --- depthwise 3x3 + GELU-GLU; wave w -> output rows 2w, 2w+1 ---
        float wt[9];
        #pragma unroll
        for (int t = 0; t < 9; ++t)
            wt[t] = icv ? ws[OFF_WDI + t * C2 + ic] : 0.f;

        int oy0 = w * 2;
        float rr[4][10];                  // rolling rows, conflict-free ds_read
        #pragma unroll
        for (int rrow = 0; rrow < 4; ++rrow)
            #pragma unroll
            for (int cc = 0; cc < 10; ++cc)
                rr[rrow][cc] = zs[((oy0 + rrow) * 10 + cc) * 64 + lane];

        #pragma unroll
        for (int ry = 0; ry < 2; ++ry) {
            #pragma unroll
            for (int ox = 0; ox < 8; ++ox) {
                float a = wt[0] * rr[ry][ox]     + wt[1] * rr[ry][ox + 1]     + wt[2] * rr[ry][ox + 2]
                        + wt[3] * rr[ry + 1][ox] + wt[4] * rr[ry + 1][ox + 1] + wt[5] * rr[ry + 1][ox + 2]
                        + wt[6] * rr[ry + 2][ox] + wt[7] * rr[ry + 2][ox + 1] + wt[8] * rr[ry + 2][ox + 2];
                float prt = __shfl_xor(a, 1);     // partner (dw2) value
                if (!(lane & 1))                  // even lane owns o' = lane>>1
                    gsl[(lane >> 1) * 65 + (oy0 + ry) * 8 + ox] =
                        icv ? (gelu_exact(a) * prt) : 0.f;
            }
        }
        __syncthreads();

        // --- partial project_out over this group's 32 o-channels ---
        const float* wb = ws + OFF_WOT + (size_t)(g * 32) * 64 + ob;  // uniform
        #pragma unroll
        for (int cp = 0; cp < 32; ++cp) {
            float gv = gsl[cp * 65 + lane];
            const float* wp = wb + cp * 64;       // rows >=170 are zeros
            #pragma unroll
            for (int k = 0; k < 16; ++k) acc[k] += wp[k] * gv;
        }
    }

    int yy = gy0 + (lane >> 3), xx = gx0 + (lane & 7);
    #pragma unroll
    for (int k = 0; k < 16; ++k)
        out[((size_t)b * 64 + ob + k) * HW + (size_t)yy * IMG + xx] = acc[k];
}

// ---------------------------------------------------------------------------
extern "C" void kernel_launch(void* const* d_in, const int* in_sizes, int n_in,
                              void* d_out, int out_size, void* d_ws, size_t ws_size,
                              hipStream_t stream) {
    const float* x    = (const float*)d_in[0];
    const float* Win  = (const float*)d_in[1];
    const float* Wdw  = (const float*)d_in[2];
    const float* ff   = (const float*)d_in[3];
    const float* Wout = (const float*)d_in[4];
    float* out = (float*)d_out;
    float* ws  = (float*)d_ws;
    float* zbuf = ws + OFF_Z;

    hipLaunchKernelGGL(k_prep_k, dim3(ICP), dim3(64), 0, stream, ff, ws);
    hipLaunchKernelGGL(k_prep_w, dim3(96), dim3(256), 0, stream, Win, Wdw, Wout, ws);

    // Adaptive z-chunking: chunk of R patch rows needs (R+2, capped 32) rows.
    size_t capf = ws_size / sizeof(float);
    capf = (capf > OFF_Z) ? capf - OFF_Z : 0;
    const size_t perRow = (size_t)C2 * 2048;
    int R;
    if (capf >= perRow * 32) {
        R = 32;
    } else {
        long t = (long)(capf / perRow) - 2;
        R = (t < 1) ? 1 : (t > 32 ? 32 : (int)t);
    }

    for (int b = 0; b < 4; ++b) {
        for (int pr = 0; pr < 32; pr += R) {
            int tr1 = (pr + R < 32) ? pr + R : 32;
            int pr0h = (pr > 0) ? pr - 1 : 0;
            int pr1h = (tr1 < 32) ? tr1 + 1 : 32;
            int nrh = pr1h - pr0h;
            int ntr = tr1 - pr;
            hipLaunchKernelGGL(k_proj_conv, dim3(nrh * 32), dim3(384), 0, stream,
                               x, ws, zbuf, b, pr0h, nrh);
            hipLaunchKernelGGL(k_post, dim3(ntr * 32), dim3(256), 0, stream,
                               zbuf, ws, out, b, pr, pr0h, nrh);
        }
    }
}